// Round 11
// baseline (129.441 us; speedup 1.0000x reference)
//
#include <hip/hip_runtime.h>

// Problem constants (B=2, S=2048, H=8, E=64).
#define S_LEN 2048
#define NH    8
#define EMB   64
#define BM    64    // q rows per block-column (16 per wave)
#define BN    64    // kv tile length
#define NKT   (S_LEN / BN)          // 32 kv tiles
#define NSPLIT 2    // fallback-path KV splits
#define NG    4     // fused-path wave-groups per block (KV 4-way split)
#define M_INIT  (-1.0e4f)
#define EXP_CLAMP (-80.0f)
#define DEFER_THR 8.0f

typedef _Float16 half8   __attribute__((ext_vector_type(8)));
typedef _Float16 half4   __attribute__((ext_vector_type(4)));
typedef float    float4_t __attribute__((ext_vector_type(4)));
typedef float    float8_t __attribute__((ext_vector_type(8)));

__device__ inline half8 cvt8(const float* p) {
    float8_t f = *reinterpret_cast<const float8_t*>(p);
    half8 h;
    #pragma unroll
    for (int j = 0; j < 8; ++j) h[j] = (_Float16)f[j];
    return h;
}

__device__ inline void gload_lds16(const _Float16* g, _Float16* l) {
    __builtin_amdgcn_global_load_lds(
        (const __attribute__((address_space(1))) void*)g,
        (__attribute__((address_space(3))) void*)l, 16, 0, 0);
}

// ---------------------------------------------------------------------------
// Projection worker (unchanged, verified):
//   mode 0: Q -> Qf16[bh][s][e], f16, pre-scaled by 0.125
//   mode 1: K -> KT8[bh][f/8][s][f%8]
//   mode 2: V -> VT8[bh][s/8][f][s%8]
// ---------------------------------------------------------------------------
__device__ inline void proj_body(
    int mode, int bid, const float* __restrict__ X,
    const float* __restrict__ W, const float* __restrict__ bias,
    _Float16* __restrict__ Dst)
{
    const int tid  = threadIdx.x;
    const int lane = tid & 63;
    const int wave = tid >> 6;
    const int l15  = lane & 15;
    const int quad = lane >> 4;
    const int gwave = bid * 4 + wave;

    half8 wf[4][2];
    #pragma unroll
    for (int ft = 0; ft < 4; ++ft)
        #pragma unroll
        for (int ks = 0; ks < 2; ++ks)
            wf[ft][ks] = cvt8(W + (ft * 16 + l15) * 64 + ks * 32 + quad * 8);
    float bv[4];
    #pragma unroll
    for (int ft = 0; ft < 4; ++ft) bv[ft] = bias[ft * 16 + l15];

    #pragma unroll
    for (int rt2 = 0; rt2 < 2; ++rt2) {
        const int rt = gwave * 2 + rt2;
        const int arow = rt * 16 + l15;
        half8 xf[2];
        #pragma unroll
        for (int ks = 0; ks < 2; ++ks)
            xf[ks] = cvt8(X + (long)arow * 64 + ks * 32 + quad * 8);
        float4_t acc[4];
        #pragma unroll
        for (int ft = 0; ft < 4; ++ft) {
            acc[ft] = (float4_t){0.f, 0.f, 0.f, 0.f};
            #pragma unroll
            for (int ks = 0; ks < 2; ++ks)
                acc[ft] = __builtin_amdgcn_mfma_f32_16x16x32_f16(
                    xf[ks], wf[ft][ks], acc[ft], 0, 0, 0);
        }
        #pragma unroll
        for (int r = 0; r < 4; ++r) {
            const int row = rt * 16 + quad * 4 + r;     // (b*S+s)*H+h
            const int b = row >> 14;
            const int s = (row >> 3) & 2047;
            const int h = row & 7;
            const int bh = b * NH + h;
            #pragma unroll
            for (int ft = 0; ft < 4; ++ft) {
                const _Float16 v = (_Float16)(acc[ft][r] + bv[ft]);
                const int f = ft * 16 + l15;
                if (mode == 0)
                    Dst[((long)bh * S_LEN + s) * EMB + f] = v * (_Float16)0.125f;
                else if (mode == 1)
                    Dst[(((long)bh * 8 + (f >> 3)) * S_LEN + s) * 8 + (f & 7)] = v;
                else
                    Dst[(((long)bh * 256 + (s >> 3)) * 64 + f) * 8 + (s & 7)] = v;
            }
        }
    }
}

__global__ __launch_bounds__(256) void proj_qkv(
    const float* __restrict__ q_in, const float* __restrict__ k_in,
    const float* __restrict__ v_in,
    const float* __restrict__ Wq, const float* __restrict__ bq,
    const float* __restrict__ Wk, const float* __restrict__ bk,
    const float* __restrict__ Wv, const float* __restrict__ bv_,
    _Float16* __restrict__ Qf16, _Float16* __restrict__ KT8,
    _Float16* __restrict__ VT8)
{
    const int seg = blockIdx.x >> 8;
    const int bid = blockIdx.x & 255;
    if (seg == 0)      proj_body(0, bid, q_in, Wq, bq, Qf16);
    else if (seg == 1) proj_body(1, bid, k_in, Wk, bk, KT8);
    else               proj_body(2, bid, v_in, Wv, bv_, VT8);
}

__global__ __launch_bounds__(256) void proj_qk(
    const float* __restrict__ q_in, const float* __restrict__ k_in,
    const float* __restrict__ Wq, const float* __restrict__ bq,
    const float* __restrict__ Wk, const float* __restrict__ bk,
    _Float16* __restrict__ Qf16, _Float16* __restrict__ KT8)
{
    const int seg = blockIdx.x >> 8;
    const int bid = blockIdx.x & 255;
    if (seg == 0) proj_body(0, bid, q_in, Wq, bq, Qf16);
    else          proj_body(1, bid, k_in, Wk, bk, KT8);
}

__global__ __launch_bounds__(256) void proj_v(
    const float* __restrict__ v_in,
    const float* __restrict__ Wv, const float* __restrict__ bv_,
    _Float16* __restrict__ VT8)
{
    proj_body(2, blockIdx.x, v_in, Wv, bv_, VT8);
}

// ---------------------------------------------------------------------------
// FUSED attention, R11: 1024-thread blocks, 4 wave-groups of 4; group g owns
// KV tiles [8g, 8g+8) with its own K/V double-buffer. Serial depth per block
// halves (16 -> 8 steps) at constant per-step per-CU work — attacks the fixed
// per-step latency cost proven by R4. LDS = 4x32KB K/V + 16x2KB P = 163840 B
// (full CU; 1 block/CU, 16 waves/CU — same occupancy as R10; 160KB/WG is
// launchable on MI355X per AITER fmha). 4-way merge: groups 1-3 publish
// unnormalized (O, m, l) into their own dead K/V regions; group 0 merges via
// the split-softmax identity and writes f32 out. Grid 512 = 2 rounds of 256.
// Per-tile schedule is R8's verified one (single-exposed P round-trip etc.).
// ---------------------------------------------------------------------------
__global__ __launch_bounds__(1024, 4) void attn_fused4(
    const _Float16* __restrict__ KT, const _Float16* __restrict__ VT,
    const _Float16* __restrict__ Qf16, float* __restrict__ out)
{
    extern __shared__ __align__(16) char smem[];
    // [g*32768, +8192) Kb0 | +8192 Kb1 | +16384 Vb0 | +24576 Vb1 (g=0..3)
    // [131072, 163840): per-wave P, wave w at 131072 + w*2048
    // publish (post-loop, group g>0 region): O_g f32 16KB @ g*32768
    //   (+w4*4096); m/l f32 @ g*32768+16384 (+w4*128): 16 m then 16 l.

    const int tid  = threadIdx.x;
    const int lane = tid & 63;
    const int wave = tid >> 6;          // 0..15
    const int g    = wave >> 2;         // KV-split group 0..3
    const int w4   = wave & 3;          // wave within group
    const int l15  = lane & 15;
    const int quad = lane >> 4;
    const int tid_g = tid & 255;        // thread id within group

    _Float16* Kb0 = (_Float16*)(smem + g * 32768);
    _Float16* Kb1 = (_Float16*)(smem + g * 32768 + 8192);
    _Float16* Vb0 = (_Float16*)(smem + g * 32768 + 16384);
    _Float16* Vb1 = (_Float16*)(smem + g * 32768 + 24576);
    _Float16* Pw  = (_Float16*)(smem + 131072 + wave * 2048);

    // XCD-aware decomposition: 512 = 8 XCD * (2 heads * 32 qt)
    const int bx  = blockIdx.x;
    const int xcd = bx & 7;
    const int j   = bx >> 3;            // 0..63
    const int hh  = j >> 5;
    const int qt  = j & 31;
    const int bh  = xcd * 2 + hh;

    const int qrow0 = qt * BM + w4 * 16;          // same rows for all groups
    const _Float16* kg  = KT + (long)bh * 8 * S_LEN * 8;
    const _Float16* vgh = VT + (long)bh * 256 * 512;

    const _Float16* k0 = kg + ((long)(tid_g >> 6) * S_LEN + (tid_g & 63)) * 8;
    const _Float16* k1 = kg + ((long)((tid_g >> 6) + 4) * S_LEN + (tid_g & 63)) * 8;
    const _Float16* v0 = vgh + tid_g * 8;
    const _Float16* v1 = vgh + (256 + tid_g) * 8;

    const int kb = g * (NKT / NG);                // 8 tiles per group

    // ---- prologue: stage tile kb into buffer 0; load Q frags meanwhile ----
    {
        const long t8  = (long)(kb * BN) * 8;
        const long t64 = (long)(kb * BN) * 64;
        gload_lds16(k0 + t8,  Kb0 + tid_g * 8);
        gload_lds16(k1 + t8,  Kb0 + (256 + tid_g) * 8);
        gload_lds16(v0 + t64, Vb0 + tid_g * 8);
        gload_lds16(v1 + t64, Vb0 + (256 + tid_g) * 8);
    }

    half8 qf[2];
    {
        const _Float16* qrow = Qf16 + ((long)bh * S_LEN + qrow0 + l15) * EMB;
        qf[0] = *reinterpret_cast<const half8*>(qrow + quad * 8);
        qf[1] = *reinterpret_cast<const half8*>(qrow + 32 + quad * 8);
    }

    half8 vones;
    #pragma unroll
    for (int jj = 0; jj < 8; ++jj) vones[jj] = (_Float16)1.0f;

    float4_t o[4];
    #pragma unroll
    for (int et = 0; et < 4; ++et) o[et] = (float4_t){0.f, 0.f, 0.f, 0.f};
    float4_t lacc = (float4_t){0.f, 0.f, 0.f, 0.f};
    float m_run = M_INIT;

    const int pswz = (l15 & 7) << 3;
    __syncthreads();                      // drains prologue vmcnt

    for (int it = 0; it < NKT / NG; ++it) {
        const int cur = it & 1;
        const bool more = (it + 1 < NKT / NG);

        if (more) {
            const long t8  = (long)((kb + it + 1) * BN) * 8;
            const long t64 = (long)((kb + it + 1) * BN) * 64;
            _Float16* kd = cur ? Kb0 : Kb1;
            _Float16* vd = cur ? Vb0 : Vb1;
            gload_lds16(k0 + t8,  kd + tid_g * 8);
            gload_lds16(k1 + t8,  kd + (256 + tid_g) * 8);
            gload_lds16(v0 + t64, vd + tid_g * 8);
            gload_lds16(v1 + t64, vd + (256 + tid_g) * 8);
        }

        const _Float16* Kc = cur ? Kb1 : Kb0;
        const _Float16* Vc = cur ? Vb1 : Vb0;

        // ---- S^T = K Q^T ----
        float4_t sacc[4];
        #pragma unroll
        for (int nt = 0; nt < 4; ++nt) sacc[nt] = (float4_t){0.f, 0.f, 0.f, 0.f};
        __builtin_amdgcn_s_setprio(1);
        #pragma unroll
        for (int nt = 0; nt < 4; ++nt)
            #pragma unroll
            for (int ks = 0; ks < 2; ++ks) {
                half8 kf = *reinterpret_cast<const half8*>(
                    Kc + (ks * 4 + quad) * 512 + (nt * 16 + l15) * 8);
                sacc[nt] = __builtin_amdgcn_mfma_f32_16x16x32_f16(
                    kf, qf[ks], sacc[nt], 0, 0, 0);
            }
        __builtin_amdgcn_s_setprio(0);

        // ---- local max (fused max3 tree) ----
        float mx = fmaxf(fmaxf(sacc[0][0], sacc[0][1]),
                         fmaxf(sacc[0][2], sacc[0][3]));
        mx = fmaxf(fmaxf(mx, sacc[1][0]), sacc[1][1]);
        mx = fmaxf(fmaxf(mx, sacc[1][2]), sacc[1][3]);
        mx = fmaxf(fmaxf(mx, sacc[2][0]), sacc[2][1]);
        mx = fmaxf(fmaxf(mx, sacc[2][2]), sacc[2][3]);
        mx = fmaxf(fmaxf(mx, sacc[3][0]), sacc[3][1]);
        mx = fmaxf(fmaxf(mx, sacc[3][2]), sacc[3][3]);

        // T13 defer (per-wave vote)
        if (!__all(mx - m_run <= DEFER_THR)) {
            float mr = fmaxf(mx, __shfl_xor(mx, 16));
            mr = fmaxf(mr, __shfl_xor(mr, 32));
            const float mn = fmaxf(m_run, mr);
            const float alpha = __expf(fmaxf(m_run - mn, EXP_CLAMP));
            m_run = mn;
            #pragma unroll
            for (int r = 0; r < 4; ++r) {
                const float ar = __shfl(alpha, quad * 4 + r);
                lacc[r] *= ar;
                #pragma unroll
                for (int et = 0; et < 4; ++et) o[et][r] *= ar;
            }
        }

        // ---- exp + ALL P stores -> ONE LDS wait -> both A-frags ----
        #pragma unroll
        for (int nt = 0; nt < 4; ++nt) {
            half4 ph;
            #pragma unroll
            for (int r = 0; r < 4; ++r)
                ph[r] = (_Float16)__expf(sacc[nt][r] - m_run);
            *reinterpret_cast<half4*>(
                &Pw[l15 * 64 + ((nt * 16 + quad * 4) ^ pswz)]) = ph;
        }
        half8 pf0 = *reinterpret_cast<const half8*>(
            &Pw[l15 * 64 + ((quad * 8) ^ pswz)]);
        half8 pf1 = *reinterpret_cast<const half8*>(
            &Pw[l15 * 64 + ((32 + quad * 8) ^ pswz)]);

        // ---- PV + l: 20 MFMAs in one burst ----
        __builtin_amdgcn_s_setprio(1);
        #pragma unroll
        for (int et = 0; et < 4; ++et) {
            half8 vf = *reinterpret_cast<const half8*>(
                Vc + quad * 512 + (et * 16 + l15) * 8);
            o[et] = __builtin_amdgcn_mfma_f32_16x16x32_f16(pf0, vf, o[et], 0, 0, 0);
        }
        lacc = __builtin_amdgcn_mfma_f32_16x16x32_f16(pf0, vones, lacc, 0, 0, 0);
        #pragma unroll
        for (int et = 0; et < 4; ++et) {
            half8 vf = *reinterpret_cast<const half8*>(
                Vc + (4 + quad) * 512 + (et * 16 + l15) * 8);
            o[et] = __builtin_amdgcn_mfma_f32_16x16x32_f16(pf1, vf, o[et], 0, 0, 0);
        }
        lacc = __builtin_amdgcn_mfma_f32_16x16x32_f16(pf1, vones, lacc, 0, 0, 0);
        __builtin_amdgcn_s_setprio(0);

        if (more) __syncthreads();
    }

    // ---- publish: groups 1-3 write unnormalized (O, m, l) to own region ----
    __syncthreads();    // everyone done reading loop buffers
    if (g > 0) {
        float* mo = (float*)(smem + g * 32768) + w4 * 1024;   // 16x64 f32
        #pragma unroll
        for (int r = 0; r < 4; ++r)
            #pragma unroll
            for (int et = 0; et < 4; ++et)
                mo[(quad * 4 + r) * 64 + et * 16 + l15] = o[et][r];
        float* ml = (float*)(smem + g * 32768 + 16384) + w4 * 32;
        if (lane < 16) ml[lane] = m_run;                       // m[row]
        if (l15 == 0) {                                        // l[row]
            #pragma unroll
            for (int r = 0; r < 4; ++r)
                ml[16 + quad * 4 + r] = lacc[r];
        }
    }
    __syncthreads();

    // ---- merge: group 0 combines 4 partials, writes f32 out ----
    if (g == 0) {
        #pragma unroll
        for (int r = 0; r < 4; ++r) {
            const int row = quad * 4 + r;
            const float m0r = __shfl(m_run, row);
            float mg[3], lg[3];
            #pragma unroll
            for (int gg = 0; gg < 3; ++gg) {
                const float* ml = (float*)(smem + (gg + 1) * 32768 + 16384)
                                  + w4 * 32;
                mg[gg] = ml[row];
                lg[gg] = ml[16 + row];
            }
            float M = fmaxf(fmaxf(m0r, mg[0]), fmaxf(mg[1], mg[2]));
            const float e0 = __expf(fmaxf(m0r - M, EXP_CLAMP));
            float e[3], denom = lacc[r] * e0;
            #pragma unroll
            for (int gg = 0; gg < 3; ++gg) {
                e[gg] = __expf(fmaxf(mg[gg] - M, EXP_CLAMP));
                denom += lg[gg] * e[gg];
            }
            const float inv = 1.f / denom;
            const long orow = ((long)bh * S_LEN + qrow0 + row) * EMB;
            #pragma unroll
            for (int et = 0; et < 4; ++et) {
                float val = o[et][r] * e0;
                #pragma unroll
                for (int gg = 0; gg < 3; ++gg) {
                    const float* mo = (float*)(smem + (gg + 1) * 32768)
                                      + w4 * 1024;
                    val += mo[row * 64 + et * 16 + l15] * e[gg];
                }
                out[orow + et * 16 + l15] = (float)(_Float16)(val * inv);
            }
        }
    }
}

// ---------------------------------------------------------------------------
// Fallback attention (R9 plan, ws too small): split across blocks + combine.
// ---------------------------------------------------------------------------
__global__ __launch_bounds__(256, 4) void attn_part(
    const _Float16* __restrict__ KT, const _Float16* __restrict__ VT,
    const _Float16* __restrict__ Qf16,
    _Float16* __restrict__ p0, _Float16* __restrict__ p1,
    float* __restrict__ stats)
{
    __shared__ __align__(16) _Float16 Kb[2][8 * 64 * 8];
    __shared__ __align__(16) _Float16 Vb[2][8 * 64 * 8];
    __shared__ __align__(16) _Float16 Pl[4][16 * 64];

    const int tid  = threadIdx.x;
    const int lane = tid & 63;
    const int wave = tid >> 6;
    const int l15  = lane & 15;
    const int quad = lane >> 4;

    const int bx     = blockIdx.x;
    const int xcd    = bx & 7;
    const int j      = bx >> 3;
    const int hh     = j >> 6;
    const int within = j & 63;
    const int bh     = xcd * 2 + hh;
    const int qt     = within >> 1;
    const int sp     = within & 1;

    const int qrow0 = qt * BM + wave * 16;
    const _Float16* kg  = KT + (long)bh * 8 * S_LEN * 8;
    const _Float16* vgh = VT + (long)bh * 256 * 512;

    const _Float16* k0 = kg + ((long)(tid >> 6) * S_LEN + (tid & 63)) * 8;
    const _Float16* k1 = kg + ((long)((tid >> 6) + 4) * S_LEN + (tid & 63)) * 8;
    const _Float16* v0 = vgh + tid * 8;
    const _Float16* v1 = vgh + (256 + tid) * 8;

    const int kb = sp * (NKT / NSPLIT), ke = kb + (NKT / NSPLIT);

    {
        const long t8  = (long)(kb * BN) * 8;
        const long t64 = (long)(kb * BN) * 64;
        gload_lds16(k0 + t8,  &Kb[0][tid * 8]);
        gload_lds16(k1 + t8,  &Kb[0][(256 + tid) * 8]);
        gload_lds16(v0 + t64, &Vb[0][tid * 8]);
        gload_lds16(v1 + t64, &Vb[0][(256 + tid) * 8]);
    }

    half8 qf[2];
    {
        const _Float16* qrow = Qf16 + ((long)bh * S_LEN + qrow0 + l15) * EMB;
        qf[0] = *reinterpret_cast<const half8*>(qrow + quad * 8);
        qf[1] = *reinterpret_cast<const half8*>(qrow + 32 + quad * 8);
    }

    half8 vones;
    #pragma unroll
    for (int jj = 0; jj < 8; ++jj) vones[jj] = (_Float16)1.0f;

    float4_t o[4];
    #pragma unroll
    for (int et = 0; et < 4; ++et) o[et] = (float4_t){0.f, 0.f, 0.f, 0.f};
    float4_t lacc = (float4_t){0.f, 0.f, 0.f, 0.f};
    float m_run = M_INIT;

    const int pswz = (l15 & 7) << 3;
    _Float16* Pw = Pl[wave];

    __syncthreads();

    for (int kt = kb; kt < ke; ++kt) {
        const int cur = (kt - kb) & 1;
        const bool more = (kt + 1 < ke);

        if (more) {
            const long t8  = (long)((kt + 1) * BN) * 8;
            const long t64 = (long)((kt + 1) * BN) * 64;
            _Float16* kd = Kb[cur ^ 1];
            _Float16* vd = Vb[cur ^ 1];
            gload_lds16(k0 + t8,  kd + tid * 8);
            gload_lds16(k1 + t8,  kd + (256 + tid) * 8);
            gload_lds16(v0 + t64, vd + tid * 8);
            gload_lds16(v1 + t64, vd + (256 + tid) * 8);
        }

        const _Float16* Kc = Kb[cur];
        const _Float16* Vc = Vb[cur];

        float4_t sacc[4];
        #pragma unroll
        for (int nt = 0; nt < 4; ++nt) sacc[nt] = (float4_t){0.f, 0.f, 0.f, 0.f};
        __builtin_amdgcn_s_setprio(1);
        #pragma unroll
        for (int nt = 0; nt < 4; ++nt)
            #pragma unroll
            for (int ks = 0; ks < 2; ++ks) {
                half8 kf = *reinterpret_cast<const half8*>(
                    Kc + (ks * 4 + quad) * 512 + (nt * 16 + l15) * 8);
                sacc[nt] = __builtin_amdgcn_mfma_f32_16x16x32_f16(
                    kf, qf[ks], sacc[nt], 0, 0, 0);
            }
        __builtin_amdgcn_s_setprio(0);

        float mx = fmaxf(fmaxf(sacc[0][0], sacc[0][1]),
                         fmaxf(sacc[0][2], sacc[0][3]));
        mx = fmaxf(fmaxf(mx, sacc[1][0]), sacc[1][1]);
        mx = fmaxf(fmaxf(mx, sacc[1][2]), sacc[1][3]);
        mx = fmaxf(fmaxf(mx, sacc[2][0]), sacc[2][1]);
        mx = fmaxf(fmaxf(mx, sacc[2][2]), sacc[2][3]);
        mx = fmaxf(fmaxf(mx, sacc[3][0]), sacc[3][1]);
        mx = fmaxf(fmaxf(mx, sacc[3][2]), sacc[3][3]);

        if (!__all(mx - m_run <= DEFER_THR)) {
            float mr = fmaxf(mx, __shfl_xor(mx, 16));
            mr = fmaxf(mr, __shfl_xor(mr, 32));
            const float mn = fmaxf(m_run, mr);
            const float alpha = __expf(fmaxf(m_run - mn, EXP_CLAMP));
            m_run = mn;
            #pragma unroll
            for (int r = 0; r < 4; ++r) {
                const float ar = __shfl(alpha, quad * 4 + r);
                lacc[r] *= ar;
                #pragma unroll
                for (int et = 0; et < 4; ++et) o[et][r] *= ar;
            }
        }

        #pragma unroll
        for (int nt = 0; nt < 4; ++nt) {
            half4 ph;
            #pragma unroll
            for (int r = 0; r < 4; ++r)
                ph[r] = (_Float16)__expf(sacc[nt][r] - m_run);
            *reinterpret_cast<half4*>(
                &Pw[l15 * 64 + ((nt * 16 + quad * 4) ^ pswz)]) = ph;
        }
        half8 pf0 = *reinterpret_cast<const half8*>(
            &Pw[l15 * 64 + ((quad * 8) ^ pswz)]);
        half8 pf1 = *reinterpret_cast<const half8*>(
            &Pw[l15 * 64 + ((32 + quad * 8) ^ pswz)]);

        __builtin_amdgcn_s_setprio(1);
        #pragma unroll
        for (int et = 0; et < 4; ++et) {
            half8 vf = *reinterpret_cast<const half8*>(
                Vc + quad * 512 + (et * 16 + l15) * 8);
            o[et] = __builtin_amdgcn_mfma_f32_16x16x32_f16(pf0, vf, o[et], 0, 0, 0);
        }
        lacc = __builtin_amdgcn_mfma_f32_16x16x32_f16(pf0, vones, lacc, 0, 0, 0);
        #pragma unroll
        for (int et = 0; et < 4; ++et) {
            half8 vf = *reinterpret_cast<const half8*>(
                Vc + (4 + quad) * 512 + (et * 16 + l15) * 8);
            o[et] = __builtin_amdgcn_mfma_f32_16x16x32_f16(pf1, vf, o[et], 0, 0, 0);
        }
        lacc = __builtin_amdgcn_mfma_f32_16x16x32_f16(pf1, vones, lacc, 0, 0, 0);
        __builtin_amdgcn_s_setprio(0);

        if (more) __syncthreads();
    }

    _Float16* pp = (sp == 0) ? p0 : p1;
    #pragma unroll
    for (int r = 0; r < 4; ++r) {
        const float inv = 1.f / lacc[r];
        const int row = qrow0 + quad * 4 + r;
        const int R = bh * S_LEN + row;
        #pragma unroll
        for (int et = 0; et < 4; ++et)
            pp[(long)R * EMB + et * 16 + l15] = (_Float16)(o[et][r] * inv);
    }
    {
        const int srcl = (lane >> 2) * 16;
        const float s0 = __shfl(lacc[0], srcl);
        const float s1 = __shfl(lacc[1], srcl);
        const float s2 = __shfl(lacc[2], srcl);
        const float s3 = __shfl(lacc[3], srcl);
        const int rr = lane & 3;
        const float lsel = (rr == 0) ? s0 : (rr == 1) ? s1 : (rr == 2) ? s2 : s3;
        if (lane < 16) {
            const int R = bh * S_LEN + qrow0 + lane;
            stats[sp * 32768 + R] = m_run;
            stats[(NSPLIT + sp) * 32768 + R] = lsel;
        }
    }
}

__global__ __launch_bounds__(256) void attn_combine(
    const _Float16* __restrict__ p0, const _Float16* __restrict__ p1,
    const float* __restrict__ stats, float* __restrict__ out)
{
    const int gid = blockIdx.x * 256 + threadIdx.x;
    const int R  = gid >> 2;
    const int c0 = (gid & 3) * 16;
    const float m0 = stats[R], m1 = stats[32768 + R];
    const float l0 = stats[2 * 32768 + R], l1 = stats[3 * 32768 + R];
    const float M = fmaxf(m0, m1);
    float w0 = l0 * __expf(fmaxf(m0 - M, EXP_CLAMP));
    float w1 = l1 * __expf(fmaxf(m1 - M, EXP_CLAMP));
    const float rinv = 1.f / (w0 + w1);
    w0 *= rinv; w1 *= rinv;
    const long i0 = (long)R * EMB + c0;
    #pragma unroll
    for (int h = 0; h < 2; ++h) {
        half8 a = *reinterpret_cast<const half8*>(p0 + i0 + h * 8);
        half8 b = *reinterpret_cast<const half8*>(p1 + i0 + h * 8);
        #pragma unroll
        for (int j = 0; j < 8; ++j)
            out[i0 + h * 8 + j] = (float)(_Float16)(
                w0 * (float)a[j] + w1 * (float)b[j]);
    }
}

// ---------------------------------------------------------------------------
// Primary (ws >= 12 MiB): proj_qkv -> attn_fused4 (2 launches, 160KB LDS).
// Fallback: R9 plan.
// ---------------------------------------------------------------------------
extern "C" void kernel_launch(void* const* d_in, const int* in_sizes, int n_in,
                              void* d_out, int out_size, void* d_ws, size_t ws_size,
                              hipStream_t stream) {
    const float* q_in = (const float*)d_in[0];
    const float* k_in = (const float*)d_in[1];
    const float* v_in = (const float*)d_in[2];
    const float* Wq   = (const float*)d_in[3];
    const float* bq   = (const float*)d_in[4];
    const float* Wk   = (const float*)d_in[5];
    const float* bk   = (const float*)d_in[6];
    const float* Wv   = (const float*)d_in[7];
    const float* bv   = (const float*)d_in[8];
    float* out = (float*)d_out;

    if (ws_size >= (size_t)(12u << 20)) {
        _Float16* Qf16 = (_Float16*)d_ws;                         // 4 MiB
        _Float16* KT8  = (_Float16*)((char*)d_ws + (4u << 20));   // 4 MiB
        _Float16* VT8  = (_Float16*)((char*)d_ws + (8u << 20));   // 4 MiB
        // allow full-LDS dynamic allocation (no-op if already permitted)
        static bool attr_set = false;
        if (!attr_set) {
            (void)hipFuncSetAttribute((const void*)attn_fused4,
                hipFuncAttributeMaxDynamicSharedMemorySize, 163840);
            attr_set = true;
        }
        proj_qkv<<<768, 256, 0, stream>>>(q_in, k_in, v_in, Wq, bq, Wk, bk,
                                          Wv, bv, Qf16, KT8, VT8);
        attn_fused4<<<512, 1024, 163840, stream>>>(KT8, VT8, Qf16, out);
    } else {
        _Float16* Qf16  = (_Float16*)d_out;
        _Float16* KT8   = (_Float16*)((char*)d_out + (4u << 20));
        _Float16* part0 = (_Float16*)d_in[2];
        _Float16* part1 = part0 + (long)2 * 1024 * 1024;
        float*    stats = (float*)d_in[0];
        _Float16* VT8;
        if (ws_size >= (size_t)(4u << 20)) {
            VT8 = (_Float16*)d_ws;
            proj_qkv<<<768, 256, 0, stream>>>(q_in, k_in, v_in, Wq, bq, Wk, bk,
                                              Wv, bv, Qf16, KT8, VT8);
        } else {
            VT8 = (_Float16*)d_in[1];
            proj_qk<<<512, 256, 0, stream>>>(q_in, k_in, Wq, bq, Wk, bk,
                                             Qf16, KT8);
            proj_v<<<256, 256, 0, stream>>>(v_in, Wv, bv, VT8);
        }
        attn_part<<<16 * 32 * NSPLIT, 256, 0, stream>>>(KT8, VT8, Qf16,
                                                        part0, part1, stats);
        attn_combine<<<512, 256, 0, stream>>>(part0, part1, stats, out);
    }
}

// Round 12
// 119.895 us; speedup vs baseline: 1.0796x; 1.0796x over previous
//
#include <hip/hip_runtime.h>

// Problem constants (B=2, S=2048, H=8, E=64).
#define S_LEN 2048
#define NH    8
#define EMB   64
#define BM    64    // q rows per block-column (16 per wave)
#define BN    64    // kv tile length
#define NKT   (S_LEN / BN)          // 32 kv tiles
#define NSPLIT 2    // KV splits (intra-block groups on the fused path)
#define M_INIT  (-1.0e4f)
#define EXP_CLAMP (-80.0f)
#define DEFER_THR 8.0f

typedef _Float16 half8   __attribute__((ext_vector_type(8)));
typedef _Float16 half4   __attribute__((ext_vector_type(4)));
typedef float    float4_t __attribute__((ext_vector_type(4)));
typedef float    float8_t __attribute__((ext_vector_type(8)));

__device__ inline half8 cvt8(const float* p) {
    float8_t f = *reinterpret_cast<const float8_t*>(p);
    half8 h;
    #pragma unroll
    for (int j = 0; j < 8; ++j) h[j] = (_Float16)f[j];
    return h;
}

__device__ inline void gload_lds16(const _Float16* g, _Float16* l) {
    __builtin_amdgcn_global_load_lds(
        (const __attribute__((address_space(1))) void*)g,
        (__attribute__((address_space(3))) void*)l, 16, 0, 0);
}

// ---------------------------------------------------------------------------
// Projection worker (unchanged, verified):
//   mode 0: Q -> Qf16[bh][s][e], f16, pre-scaled by 0.125
//   mode 1: K -> KT8[bh][f/8][s][f%8]
//   mode 2: V -> VT8[bh][s/8][f][s%8]
// ---------------------------------------------------------------------------
__device__ inline void proj_body(
    int mode, int bid, const float* __restrict__ X,
    const float* __restrict__ W, const float* __restrict__ bias,
    _Float16* __restrict__ Dst)
{
    const int tid  = threadIdx.x;
    const int lane = tid & 63;
    const int wave = tid >> 6;
    const int l15  = lane & 15;
    const int quad = lane >> 4;
    const int gwave = bid * 4 + wave;

    half8 wf[4][2];
    #pragma unroll
    for (int ft = 0; ft < 4; ++ft)
        #pragma unroll
        for (int ks = 0; ks < 2; ++ks)
            wf[ft][ks] = cvt8(W + (ft * 16 + l15) * 64 + ks * 32 + quad * 8);
    float bv[4];
    #pragma unroll
    for (int ft = 0; ft < 4; ++ft) bv[ft] = bias[ft * 16 + l15];

    #pragma unroll
    for (int rt2 = 0; rt2 < 2; ++rt2) {
        const int rt = gwave * 2 + rt2;
        const int arow = rt * 16 + l15;
        half8 xf[2];
        #pragma unroll
        for (int ks = 0; ks < 2; ++ks)
            xf[ks] = cvt8(X + (long)arow * 64 + ks * 32 + quad * 8);
        float4_t acc[4];
        #pragma unroll
        for (int ft = 0; ft < 4; ++ft) {
            acc[ft] = (float4_t){0.f, 0.f, 0.f, 0.f};
            #pragma unroll
            for (int ks = 0; ks < 2; ++ks)
                acc[ft] = __builtin_amdgcn_mfma_f32_16x16x32_f16(
                    xf[ks], wf[ft][ks], acc[ft], 0, 0, 0);
        }
        #pragma unroll
        for (int r = 0; r < 4; ++r) {
            const int row = rt * 16 + quad * 4 + r;     // (b*S+s)*H+h
            const int b = row >> 14;
            const int s = (row >> 3) & 2047;
            const int h = row & 7;
            const int bh = b * NH + h;
            #pragma unroll
            for (int ft = 0; ft < 4; ++ft) {
                const _Float16 v = (_Float16)(acc[ft][r] + bv[ft]);
                const int f = ft * 16 + l15;
                if (mode == 0)
                    Dst[((long)bh * S_LEN + s) * EMB + f] = v * (_Float16)0.125f;
                else if (mode == 1)
                    Dst[(((long)bh * 8 + (f >> 3)) * S_LEN + s) * 8 + (f & 7)] = v;
                else
                    Dst[(((long)bh * 256 + (s >> 3)) * 64 + f) * 8 + (s & 7)] = v;
            }
        }
    }
}

__global__ __launch_bounds__(256) void proj_qkv(
    const float* __restrict__ q_in, const float* __restrict__ k_in,
    const float* __restrict__ v_in,
    const float* __restrict__ Wq, const float* __restrict__ bq,
    const float* __restrict__ Wk, const float* __restrict__ bk,
    const float* __restrict__ Wv, const float* __restrict__ bv_,
    _Float16* __restrict__ Qf16, _Float16* __restrict__ KT8,
    _Float16* __restrict__ VT8)
{
    const int seg = blockIdx.x >> 8;
    const int bid = blockIdx.x & 255;
    if (seg == 0)      proj_body(0, bid, q_in, Wq, bq, Qf16);
    else if (seg == 1) proj_body(1, bid, k_in, Wk, bk, KT8);
    else               proj_body(2, bid, v_in, Wv, bv_, VT8);
}

__global__ __launch_bounds__(256) void proj_qk(
    const float* __restrict__ q_in, const float* __restrict__ k_in,
    const float* __restrict__ Wq, const float* __restrict__ bq,
    const float* __restrict__ Wk, const float* __restrict__ bk,
    _Float16* __restrict__ Qf16, _Float16* __restrict__ KT8)
{
    const int seg = blockIdx.x >> 8;
    const int bid = blockIdx.x & 255;
    if (seg == 0) proj_body(0, bid, q_in, Wq, bq, Qf16);
    else          proj_body(1, bid, k_in, Wk, bk, KT8);
}

__global__ __launch_bounds__(256) void proj_v(
    const float* __restrict__ v_in,
    const float* __restrict__ Wv, const float* __restrict__ bv_,
    _Float16* __restrict__ VT8)
{
    proj_body(2, blockIdx.x, v_in, Wv, bv_, VT8);
}

// ---------------------------------------------------------------------------
// FUSED attention (R10 structure, verified 121.1; R12 adds speculative exp).
// 512-thread blocks, 2 wave-groups of 4; group g owns KV tiles [16g,16g+16)
// with its own K/V double-buffer; 81920 B LDS -> 2 blocks/CU (the second
// block covers barrier drains — R11's 1-block/CU variant regressed).
// R12 change: the 16 exps are computed SPECULATIVELY with the stale m_run,
// in parallel with the 15-deep fmax tree + vote (independent VALU streams);
// the common no-rescale path just stores them — removes the tree+vote from
// the per-tile critical chain. On trigger (rare) rescale + recompute.
// ---------------------------------------------------------------------------
__global__ __launch_bounds__(512, 4) void attn_fused(
    const _Float16* __restrict__ KT, const _Float16* __restrict__ VT,
    const _Float16* __restrict__ Qf16, float* __restrict__ out)
{
    extern __shared__ __align__(16) char smem[];
    // [0,32768): group 0 K dbuf + V dbuf; [32768,65536): group 1;
    // [65536,81920): per-wave P (wave w at 65536 + w*2048).
    // merge (post-loop, group-1 region): O1 f32 @32768 (+w4*4096),
    // m1/l1 @49152 (+w4*128): 16 m then 16 l.
    _Float16* KV = (_Float16*)smem;

    const int tid  = threadIdx.x;
    const int lane = tid & 63;
    const int wave = tid >> 6;          // 0..7
    const int g    = wave >> 2;         // KV-split group
    const int w4   = wave & 3;          // wave within group
    const int l15  = lane & 15;
    const int quad = lane >> 4;
    const int tid_g = tid & 255;

    _Float16* Kb0 = KV + (g * 4 + 0) * 4096;
    _Float16* Kb1 = KV + (g * 4 + 1) * 4096;
    _Float16* Vb0 = KV + (g * 4 + 2) * 4096;
    _Float16* Vb1 = KV + (g * 4 + 3) * 4096;
    _Float16* Pw  = (_Float16*)(smem + 65536) + wave * 1024;
    float*    mrgO  = (float*)(smem + 32768);
    float*    mrgML = (float*)(smem + 49152);

    // XCD-aware decomposition: 512 = 8 XCD * (2 heads * 32 qt)
    const int bx  = blockIdx.x;
    const int xcd = bx & 7;
    const int j   = bx >> 3;
    const int hh  = j >> 5;
    const int qt  = j & 31;
    const int bh  = xcd * 2 + hh;

    const int qrow0 = qt * BM + w4 * 16;
    const _Float16* kg  = KT + (long)bh * 8 * S_LEN * 8;
    const _Float16* vgh = VT + (long)bh * 256 * 512;

    const _Float16* k0 = kg + ((long)(tid_g >> 6) * S_LEN + (tid_g & 63)) * 8;
    const _Float16* k1 = kg + ((long)((tid_g >> 6) + 4) * S_LEN + (tid_g & 63)) * 8;
    const _Float16* v0 = vgh + tid_g * 8;
    const _Float16* v1 = vgh + (256 + tid_g) * 8;

    const int kb = g * (NKT / NSPLIT);

    {
        const long t8  = (long)(kb * BN) * 8;
        const long t64 = (long)(kb * BN) * 64;
        gload_lds16(k0 + t8,  Kb0 + tid_g * 8);
        gload_lds16(k1 + t8,  Kb0 + (256 + tid_g) * 8);
        gload_lds16(v0 + t64, Vb0 + tid_g * 8);
        gload_lds16(v1 + t64, Vb0 + (256 + tid_g) * 8);
    }

    half8 qf[2];
    {
        const _Float16* qrow = Qf16 + ((long)bh * S_LEN + qrow0 + l15) * EMB;
        qf[0] = *reinterpret_cast<const half8*>(qrow + quad * 8);
        qf[1] = *reinterpret_cast<const half8*>(qrow + 32 + quad * 8);
    }

    half8 vones;
    #pragma unroll
    for (int jj = 0; jj < 8; ++jj) vones[jj] = (_Float16)1.0f;

    float4_t o[4];
    #pragma unroll
    for (int et = 0; et < 4; ++et) o[et] = (float4_t){0.f, 0.f, 0.f, 0.f};
    float4_t lacc = (float4_t){0.f, 0.f, 0.f, 0.f};
    float m_run = M_INIT;

    const int pswz = (l15 & 7) << 3;
    __syncthreads();

    for (int it = 0; it < NKT / NSPLIT; ++it) {
        const int cur = it & 1;
        const bool more = (it + 1 < NKT / NSPLIT);

        if (more) {
            const long t8  = (long)((kb + it + 1) * BN) * 8;
            const long t64 = (long)((kb + it + 1) * BN) * 64;
            _Float16* kd = cur ? Kb0 : Kb1;
            _Float16* vd = cur ? Vb0 : Vb1;
            gload_lds16(k0 + t8,  kd + tid_g * 8);
            gload_lds16(k1 + t8,  kd + (256 + tid_g) * 8);
            gload_lds16(v0 + t64, vd + tid_g * 8);
            gload_lds16(v1 + t64, vd + (256 + tid_g) * 8);
        }

        const _Float16* Kc = cur ? Kb1 : Kb0;
        const _Float16* Vc = cur ? Vb1 : Vb0;

        // ---- S^T = K Q^T ----
        float4_t sacc[4];
        #pragma unroll
        for (int nt = 0; nt < 4; ++nt) sacc[nt] = (float4_t){0.f, 0.f, 0.f, 0.f};
        __builtin_amdgcn_s_setprio(1);
        #pragma unroll
        for (int nt = 0; nt < 4; ++nt)
            #pragma unroll
            for (int ks = 0; ks < 2; ++ks) {
                half8 kf = *reinterpret_cast<const half8*>(
                    Kc + (ks * 4 + quad) * 512 + (nt * 16 + l15) * 8);
                sacc[nt] = __builtin_amdgcn_mfma_f32_16x16x32_f16(
                    kf, qf[ks], sacc[nt], 0, 0, 0);
            }
        __builtin_amdgcn_s_setprio(0);

        // ---- speculative exps with STALE m_run (independent of max tree;
        //      fills the VALU while the fmax chain runs). Discarded values
        //      on trigger may be inf — harmless, overwritten. ----
        half4 ph[4];
        #pragma unroll
        for (int nt = 0; nt < 4; ++nt)
            #pragma unroll
            for (int r = 0; r < 4; ++r)
                ph[nt][r] = (_Float16)__expf(sacc[nt][r] - m_run);

        // ---- local max (fused max3 tree; runs in parallel with exps) ----
        float mx = fmaxf(fmaxf(sacc[0][0], sacc[0][1]),
                         fmaxf(sacc[0][2], sacc[0][3]));
        mx = fmaxf(fmaxf(mx, sacc[1][0]), sacc[1][1]);
        mx = fmaxf(fmaxf(mx, sacc[1][2]), sacc[1][3]);
        mx = fmaxf(fmaxf(mx, sacc[2][0]), sacc[2][1]);
        mx = fmaxf(fmaxf(mx, sacc[2][2]), sacc[2][3]);
        mx = fmaxf(fmaxf(mx, sacc[3][0]), sacc[3][1]);
        mx = fmaxf(fmaxf(mx, sacc[3][2]), sacc[3][3]);

        // T13 defer vote. Rare trigger path: rescale + recompute exps.
        if (!__all(mx - m_run <= DEFER_THR)) {
            float mr = fmaxf(mx, __shfl_xor(mx, 16));
            mr = fmaxf(mr, __shfl_xor(mr, 32));
            const float mn = fmaxf(m_run, mr);
            const float alpha = __expf(fmaxf(m_run - mn, EXP_CLAMP));
            m_run = mn;
            #pragma unroll
            for (int r = 0; r < 4; ++r) {
                const float ar = __shfl(alpha, quad * 4 + r);
                lacc[r] *= ar;
                #pragma unroll
                for (int et = 0; et < 4; ++et) o[et][r] *= ar;
            }
            #pragma unroll
            for (int nt = 0; nt < 4; ++nt)
                #pragma unroll
                for (int r = 0; r < 4; ++r)
                    ph[nt][r] = (_Float16)__expf(sacc[nt][r] - m_run);
        }

        // ---- ALL P stores -> ONE LDS wait -> both A-frags ----
        #pragma unroll
        for (int nt = 0; nt < 4; ++nt)
            *reinterpret_cast<half4*>(
                &Pw[l15 * 64 + ((nt * 16 + quad * 4) ^ pswz)]) = ph[nt];
        half8 pf0 = *reinterpret_cast<const half8*>(
            &Pw[l15 * 64 + ((quad * 8) ^ pswz)]);
        half8 pf1 = *reinterpret_cast<const half8*>(
            &Pw[l15 * 64 + ((32 + quad * 8) ^ pswz)]);

        // ---- PV + l: 20 MFMAs in one burst ----
        __builtin_amdgcn_s_setprio(1);
        #pragma unroll
        for (int et = 0; et < 4; ++et) {
            half8 vf = *reinterpret_cast<const half8*>(
                Vc + quad * 512 + (et * 16 + l15) * 8);
            o[et] = __builtin_amdgcn_mfma_f32_16x16x32_f16(pf0, vf, o[et], 0, 0, 0);
        }
        lacc = __builtin_amdgcn_mfma_f32_16x16x32_f16(pf0, vones, lacc, 0, 0, 0);
        #pragma unroll
        for (int et = 0; et < 4; ++et) {
            half8 vf = *reinterpret_cast<const half8*>(
                Vc + (4 + quad) * 512 + (et * 16 + l15) * 8);
            o[et] = __builtin_amdgcn_mfma_f32_16x16x32_f16(pf1, vf, o[et], 0, 0, 0);
        }
        lacc = __builtin_amdgcn_mfma_f32_16x16x32_f16(pf1, vones, lacc, 0, 0, 0);
        __builtin_amdgcn_s_setprio(0);

        if (more) __syncthreads();
    }

    // ---- intra-block combine: group 1 publishes, group 0 merges+writes ----
    __syncthreads();
    if (g == 1) {
        float* mo = mrgO + w4 * 1024;
        #pragma unroll
        for (int r = 0; r < 4; ++r)
            #pragma unroll
            for (int et = 0; et < 4; ++et)
                mo[(quad * 4 + r) * 64 + et * 16 + l15] = o[et][r];
        if (lane < 16) mrgML[w4 * 32 + lane] = m_run;
        if (l15 == 0) {
            #pragma unroll
            for (int r = 0; r < 4; ++r)
                mrgML[w4 * 32 + 16 + quad * 4 + r] = lacc[r];
        }
    }
    __syncthreads();
    if (g == 0) {
        const float* mo = mrgO + w4 * 1024;
        #pragma unroll
        for (int r = 0; r < 4; ++r) {
            const int row = quad * 4 + r;
            const float m0r = __shfl(m_run, row);
            const float m1r = mrgML[w4 * 32 + row];
            const float l1r = mrgML[w4 * 32 + 16 + row];
            const float M = fmaxf(m0r, m1r);
            const float e0 = __expf(fmaxf(m0r - M, EXP_CLAMP));
            const float e1 = __expf(fmaxf(m1r - M, EXP_CLAMP));
            const float inv = 1.f / (lacc[r] * e0 + l1r * e1);
            const float w0 = e0 * inv, w1 = e1 * inv;
            const long orow = ((long)bh * S_LEN + qrow0 + row) * EMB;
            #pragma unroll
            for (int et = 0; et < 4; ++et) {
                const float val = o[et][r] * w0 +
                                  mo[row * 64 + et * 16 + l15] * w1;
                out[orow + et * 16 + l15] = (float)(_Float16)val;
            }
        }
    }
}

// ---------------------------------------------------------------------------
// Fallback attention (R9 plan, ws too small): split across blocks + combine.
// Same speculative-exp reorder applied.
// ---------------------------------------------------------------------------
__global__ __launch_bounds__(256, 4) void attn_part(
    const _Float16* __restrict__ KT, const _Float16* __restrict__ VT,
    const _Float16* __restrict__ Qf16,
    _Float16* __restrict__ p0, _Float16* __restrict__ p1,
    float* __restrict__ stats)
{
    __shared__ __align__(16) _Float16 Kb[2][8 * 64 * 8];
    __shared__ __align__(16) _Float16 Vb[2][8 * 64 * 8];
    __shared__ __align__(16) _Float16 Pl[4][16 * 64];

    const int tid  = threadIdx.x;
    const int lane = tid & 63;
    const int wave = tid >> 6;
    const int l15  = lane & 15;
    const int quad = lane >> 4;

    const int bx     = blockIdx.x;
    const int xcd    = bx & 7;
    const int j      = bx >> 3;
    const int hh     = j >> 6;
    const int within = j & 63;
    const int bh     = xcd * 2 + hh;
    const int qt     = within >> 1;
    const int sp     = within & 1;

    const int qrow0 = qt * BM + wave * 16;
    const _Float16* kg  = KT + (long)bh * 8 * S_LEN * 8;
    const _Float16* vgh = VT + (long)bh * 256 * 512;

    const _Float16* k0 = kg + ((long)(tid >> 6) * S_LEN + (tid & 63)) * 8;
    const _Float16* k1 = kg + ((long)((tid >> 6) + 4) * S_LEN + (tid & 63)) * 8;
    const _Float16* v0 = vgh + tid * 8;
    const _Float16* v1 = vgh + (256 + tid) * 8;

    const int kb = sp * (NKT / NSPLIT), ke = kb + (NKT / NSPLIT);

    {
        const long t8  = (long)(kb * BN) * 8;
        const long t64 = (long)(kb * BN) * 64;
        gload_lds16(k0 + t8,  &Kb[0][tid * 8]);
        gload_lds16(k1 + t8,  &Kb[0][(256 + tid) * 8]);
        gload_lds16(v0 + t64, &Vb[0][tid * 8]);
        gload_lds16(v1 + t64, &Vb[0][(256 + tid) * 8]);
    }

    half8 qf[2];
    {
        const _Float16* qrow = Qf16 + ((long)bh * S_LEN + qrow0 + l15) * EMB;
        qf[0] = *reinterpret_cast<const half8*>(qrow + quad * 8);
        qf[1] = *reinterpret_cast<const half8*>(qrow + 32 + quad * 8);
    }

    half8 vones;
    #pragma unroll
    for (int jj = 0; jj < 8; ++jj) vones[jj] = (_Float16)1.0f;

    float4_t o[4];
    #pragma unroll
    for (int et = 0; et < 4; ++et) o[et] = (float4_t){0.f, 0.f, 0.f, 0.f};
    float4_t lacc = (float4_t){0.f, 0.f, 0.f, 0.f};
    float m_run = M_INIT;

    const int pswz = (l15 & 7) << 3;
    _Float16* Pw = Pl[wave];

    __syncthreads();

    for (int kt = kb; kt < ke; ++kt) {
        const int cur = (kt - kb) & 1;
        const bool more = (kt + 1 < ke);

        if (more) {
            const long t8  = (long)((kt + 1) * BN) * 8;
            const long t64 = (long)((kt + 1) * BN) * 64;
            _Float16* kd = Kb[cur ^ 1];
            _Float16* vd = Vb[cur ^ 1];
            gload_lds16(k0 + t8,  kd + tid * 8);
            gload_lds16(k1 + t8,  kd + (256 + tid) * 8);
            gload_lds16(v0 + t64, vd + tid * 8);
            gload_lds16(v1 + t64, vd + (256 + tid) * 8);
        }

        const _Float16* Kc = Kb[cur];
        const _Float16* Vc = Vb[cur];

        float4_t sacc[4];
        #pragma unroll
        for (int nt = 0; nt < 4; ++nt) sacc[nt] = (float4_t){0.f, 0.f, 0.f, 0.f};
        __builtin_amdgcn_s_setprio(1);
        #pragma unroll
        for (int nt = 0; nt < 4; ++nt)
            #pragma unroll
            for (int ks = 0; ks < 2; ++ks) {
                half8 kf = *reinterpret_cast<const half8*>(
                    Kc + (ks * 4 + quad) * 512 + (nt * 16 + l15) * 8);
                sacc[nt] = __builtin_amdgcn_mfma_f32_16x16x32_f16(
                    kf, qf[ks], sacc[nt], 0, 0, 0);
            }
        __builtin_amdgcn_s_setprio(0);

        // speculative exps with stale m_run (parallel with max tree)
        half4 ph[4];
        #pragma unroll
        for (int nt = 0; nt < 4; ++nt)
            #pragma unroll
            for (int r = 0; r < 4; ++r)
                ph[nt][r] = (_Float16)__expf(sacc[nt][r] - m_run);

        float mx = fmaxf(fmaxf(sacc[0][0], sacc[0][1]),
                         fmaxf(sacc[0][2], sacc[0][3]));
        mx = fmaxf(fmaxf(mx, sacc[1][0]), sacc[1][1]);
        mx = fmaxf(fmaxf(mx, sacc[1][2]), sacc[1][3]);
        mx = fmaxf(fmaxf(mx, sacc[2][0]), sacc[2][1]);
        mx = fmaxf(fmaxf(mx, sacc[2][2]), sacc[2][3]);
        mx = fmaxf(fmaxf(mx, sacc[3][0]), sacc[3][1]);
        mx = fmaxf(fmaxf(mx, sacc[3][2]), sacc[3][3]);

        if (!__all(mx - m_run <= DEFER_THR)) {
            float mr = fmaxf(mx, __shfl_xor(mx, 16));
            mr = fmaxf(mr, __shfl_xor(mr, 32));
            const float mn = fmaxf(m_run, mr);
            const float alpha = __expf(fmaxf(m_run - mn, EXP_CLAMP));
            m_run = mn;
            #pragma unroll
            for (int r = 0; r < 4; ++r) {
                const float ar = __shfl(alpha, quad * 4 + r);
                lacc[r] *= ar;
                #pragma unroll
                for (int et = 0; et < 4; ++et) o[et][r] *= ar;
            }
            #pragma unroll
            for (int nt = 0; nt < 4; ++nt)
                #pragma unroll
                for (int r = 0; r < 4; ++r)
                    ph[nt][r] = (_Float16)__expf(sacc[nt][r] - m_run);
        }

        #pragma unroll
        for (int nt = 0; nt < 4; ++nt)
            *reinterpret_cast<half4*>(
                &Pw[l15 * 64 + ((nt * 16 + quad * 4) ^ pswz)]) = ph[nt];
        half8 pf0 = *reinterpret_cast<const half8*>(
            &Pw[l15 * 64 + ((quad * 8) ^ pswz)]);
        half8 pf1 = *reinterpret_cast<const half8*>(
            &Pw[l15 * 64 + ((32 + quad * 8) ^ pswz)]);

        __builtin_amdgcn_s_setprio(1);
        #pragma unroll
        for (int et = 0; et < 4; ++et) {
            half8 vf = *reinterpret_cast<const half8*>(
                Vc + quad * 512 + (et * 16 + l15) * 8);
            o[et] = __builtin_amdgcn_mfma_f32_16x16x32_f16(pf0, vf, o[et], 0, 0, 0);
        }
        lacc = __builtin_amdgcn_mfma_f32_16x16x32_f16(pf0, vones, lacc, 0, 0, 0);
        #pragma unroll
        for (int et = 0; et < 4; ++et) {
            half8 vf = *reinterpret_cast<const half8*>(
                Vc + (4 + quad) * 512 + (et * 16 + l15) * 8);
            o[et] = __builtin_amdgcn_mfma_f32_16x16x32_f16(pf1, vf, o[et], 0, 0, 0);
        }
        lacc = __builtin_amdgcn_mfma_f32_16x16x32_f16(pf1, vones, lacc, 0, 0, 0);
        __builtin_amdgcn_s_setprio(0);

        if (more) __syncthreads();
    }

    _Float16* pp = (sp == 0) ? p0 : p1;
    #pragma unroll
    for (int r = 0; r < 4; ++r) {
        const float inv = 1.f / lacc[r];
        const int row = qrow0 + quad * 4 + r;
        const int R = bh * S_LEN + row;
        #pragma unroll
        for (int et = 0; et < 4; ++et)
            pp[(long)R * EMB + et * 16 + l15] = (_Float16)(o[et][r] * inv);
    }
    {
        const int srcl = (lane >> 2) * 16;
        const float s0 = __shfl(lacc[0], srcl);
        const float s1 = __shfl(lacc[1], srcl);
        const float s2 = __shfl(lacc[2], srcl);
        const float s3 = __shfl(lacc[3], srcl);
        const int rr = lane & 3;
        const float lsel = (rr == 0) ? s0 : (rr == 1) ? s1 : (rr == 2) ? s2 : s3;
        if (lane < 16) {
            const int R = bh * S_LEN + qrow0 + lane;
            stats[sp * 32768 + R] = m_run;
            stats[(NSPLIT + sp) * 32768 + R] = lsel;
        }
    }
}

__global__ __launch_bounds__(256) void attn_combine(
    const _Float16* __restrict__ p0, const _Float16* __restrict__ p1,
    const float* __restrict__ stats, float* __restrict__ out)
{
    const int gid = blockIdx.x * 256 + threadIdx.x;
    const int R  = gid >> 2;
    const int c0 = (gid & 3) * 16;
    const float m0 = stats[R], m1 = stats[32768 + R];
    const float l0 = stats[2 * 32768 + R], l1 = stats[3 * 32768 + R];
    const float M = fmaxf(m0, m1);
    float w0 = l0 * __expf(fmaxf(m0 - M, EXP_CLAMP));
    float w1 = l1 * __expf(fmaxf(m1 - M, EXP_CLAMP));
    const float rinv = 1.f / (w0 + w1);
    w0 *= rinv; w1 *= rinv;
    const long i0 = (long)R * EMB + c0;
    #pragma unroll
    for (int h = 0; h < 2; ++h) {
        half8 a = *reinterpret_cast<const half8*>(p0 + i0 + h * 8);
        half8 b = *reinterpret_cast<const half8*>(p1 + i0 + h * 8);
        #pragma unroll
        for (int j = 0; j < 8; ++j)
            out[i0 + h * 8 + j] = (float)(_Float16)(
                w0 * (float)a[j] + w1 * (float)b[j]);
    }
}

// ---------------------------------------------------------------------------
// Primary (ws >= 12 MiB): proj_qkv -> attn_fused (R10's 2-launch plan).
// Fallback: R9 plan.
// ---------------------------------------------------------------------------
extern "C" void kernel_launch(void* const* d_in, const int* in_sizes, int n_in,
                              void* d_out, int out_size, void* d_ws, size_t ws_size,
                              hipStream_t stream) {
    const float* q_in = (const float*)d_in[0];
    const float* k_in = (const float*)d_in[1];
    const float* v_in = (const float*)d_in[2];
    const float* Wq   = (const float*)d_in[3];
    const float* bq   = (const float*)d_in[4];
    const float* Wk   = (const float*)d_in[5];
    const float* bk   = (const float*)d_in[6];
    const float* Wv   = (const float*)d_in[7];
    const float* bv   = (const float*)d_in[8];
    float* out = (float*)d_out;

    if (ws_size >= (size_t)(12u << 20)) {
        _Float16* Qf16 = (_Float16*)d_ws;                         // 4 MiB
        _Float16* KT8  = (_Float16*)((char*)d_ws + (4u << 20));   // 4 MiB
        _Float16* VT8  = (_Float16*)((char*)d_ws + (8u << 20));   // 4 MiB
        proj_qkv<<<768, 256, 0, stream>>>(q_in, k_in, v_in, Wq, bq, Wk, bk,
                                          Wv, bv, Qf16, KT8, VT8);
        attn_fused<<<512, 512, 81920, stream>>>(KT8, VT8, Qf16, out);
    } else {
        _Float16* Qf16  = (_Float16*)d_out;
        _Float16* KT8   = (_Float16*)((char*)d_out + (4u << 20));
        _Float16* part0 = (_Float16*)d_in[2];
        _Float16* part1 = part0 + (long)2 * 1024 * 1024;
        float*    stats = (float*)d_in[0];
        _Float16* VT8;
        if (ws_size >= (size_t)(4u << 20)) {
            VT8 = (_Float16*)d_ws;
            proj_qkv<<<768, 256, 0, stream>>>(q_in, k_in, v_in, Wq, bq, Wk, bk,
                                              Wv, bv, Qf16, KT8, VT8);
        } else {
            VT8 = (_Float16*)d_in[1];
            proj_qk<<<512, 256, 0, stream>>>(q_in, k_in, Wq, bq, Wk, bk,
                                             Qf16, KT8);
            proj_v<<<256, 256, 0, stream>>>(v_in, Wv, bv, VT8);
        }
        attn_part<<<16 * 32 * NSPLIT, 256, 0, stream>>>(KT8, VT8, Qf16,
                                                        part0, part1, stats);
        attn_combine<<<512, 256, 0, stream>>>(part0, part1, stats, out);
    }
}